// Round 5
// baseline (213.341 us; speedup 1.0000x reference)
//
#include <hip/hip_runtime.h>

typedef __bf16 bf16;
typedef __bf16 bf16x8 __attribute__((ext_vector_type(8)));
typedef __bf16 bf16x4 __attribute__((ext_vector_type(4)));
typedef float  f32x4  __attribute__((ext_vector_type(4)));
typedef float  f32x16 __attribute__((ext_vector_type(16)));
typedef unsigned u32x2 __attribute__((ext_vector_type(2)));
typedef unsigned u32x4 __attribute__((ext_vector_type(4)));
typedef unsigned long long uptr;

#define MFMA16(a, b, c) __builtin_amdgcn_mfma_f32_16x16x32_bf16((a), (b), (c), 0, 0, 0)
#define MFMA32(a, b, c) __builtin_amdgcn_mfma_f32_32x32x16_bf16((a), (b), (c), 0, 0, 0)

__device__ __forceinline__ void gl_lds16(const void* g, void* l) {
  __builtin_amdgcn_global_load_lds(
      (__attribute__((address_space(1))) void*)(uptr)(g),
      (__attribute__((address_space(3))) void*)(uptr)(l),
      16, 0, 0);
}
__device__ __forceinline__ unsigned cvtpk_bf16(float lo, float hi) {
  unsigned r;
  asm("v_cvt_pk_bf16_f32 %0, %1, %2" : "=v"(r) : "v"(lo), "v"(hi));
  return r;
}

// ---------------------------------------------------------------------------
// Fused prep: converts, QKV weight/bias concat, Wo->WCAT (stride 1536),
// Wmp transpose, mask premultiply (exp2-domain), mv transpose, bmix.
__global__ __launch_bounds__(256) void fused_prep(
    const float* __restrict__ X, const float* __restrict__ Wq,
    const float* __restrict__ Wk, const float* __restrict__ Wv,
    const float* __restrict__ Wo, const float* __restrict__ Wma,
    const float* __restrict__ Wmp, const float* __restrict__ mask,
    const float* __restrict__ bq, const float* __restrict__ bk,
    const float* __restrict__ bv, const float* __restrict__ mv,
    const float* __restrict__ bo, const float* __restrict__ bmp,
    bf16* __restrict__ Xb, bf16* __restrict__ Wqkvb, bf16* __restrict__ WCAT,
    bf16* __restrict__ Wmab, bf16* __restrict__ WmpT,
    float* __restrict__ M2, float* __restrict__ bqkv, bf16* __restrict__ mvTb,
    float* __restrict__ bmix) {
  const int bid = blockIdx.x, t = threadIdx.x;
  auto cvt = [&](const float* src, bf16* dst, int blk) {
    const long i = ((long)blk * 256 + t) * 4;
    const float4 v = *(const float4*)(src + i);
    bf16x4 o = {(bf16)v.x, (bf16)v.y, (bf16)v.z, (bf16)v.w};
    *(bf16x4*)(dst + i) = o;
  };
  if (bid < 4096) cvt(X, Xb, bid);
  else if (bid < 5120) cvt(Wq, Wqkvb, bid - 4096);
  else if (bid < 6144) cvt(Wk, Wqkvb + 1024 * 1024, bid - 5120);
  else if (bid < 7168) cvt(Wv, Wqkvb + 2 * 1024 * 1024, bid - 6144);
  else if (bid < 8192) {  // Wo -> WCAT left half, row stride 1536
    const long i = ((long)(bid - 7168) * 256 + t) * 4;
    const long row = i >> 10, col = i & 1023;
    const float4 v = *(const float4*)(Wo + i);
    bf16x4 o = {(bf16)v.x, (bf16)v.y, (bf16)v.z, (bf16)v.w};
    *(bf16x4*)(WCAT + row * 1536 + col) = o;
  } else if (bid < 8448) cvt(Wma, Wmab, bid - 8192);
  else if (bid < 8960) {  // WmpT[m][k] = Wmp[k][m], bf16
    const int m = bid - 8448;
#pragma unroll
    for (int j = 0; j < 4; ++j) {
      const int k = t * 4 + j;
      WmpT[(long)m * 1024 + k] = (bf16)Wmp[(long)k * 512 + m];
    }
  } else if (bid < 8964) {  // mask -> exp2-domain additive
    const long i = ((long)(bid - 8960) * 256 + t) * 4;
    const float4 v = *(const float4*)(mask + i);
    float4 o = {v.x * -1.44269504e9f, v.y * -1.44269504e9f,
                v.z * -1.44269504e9f, v.w * -1.44269504e9f};
    *(float4*)(M2 + i) = o;
  } else if (bid < 8967) {  // bias concat
    const int s = bid - 8964;
    const float* src = s == 0 ? bq : (s == 1 ? bk : bv);
    *(float4*)(bqkv + s * 1024 + t * 4) = *(const float4*)(src + t * 4);
  } else if (bid < 9479) {  // memory_values transpose [256][512] -> [512][256]
    const int d = bid - 8967;
    mvTb[(long)d * 256 + t] = (bf16)mv[(long)t * 512 + d];
  } else {  // bmix[n] = bo[n] + 0.3*sum_k Wo[n][k]*bmp[k]
    const int n = (bid - 9479) * 256 + t;
    float acc = 0.0f;
    for (int k4 = 0; k4 < 256; ++k4) {
      const float4 wv = *(const float4*)(Wo + (long)n * 1024 + k4 * 4);
      const float4 bb = *(const float4*)(bmp + k4 * 4);
      acc += wv.x * bb.x + wv.y * bb.y + wv.z * bb.z + wv.w * bb.w;
    }
    bmix[n] = bo[n] + 0.3f * acc;
  }
}

// row softmax over 256 cols, fp32 in, bf16 out. one wave per row.
__global__ __launch_bounds__(256) void softmax_rows256(const float* __restrict__ in,
                                                       bf16* __restrict__ out) {
  const int w = threadIdx.x >> 6, l = threadIdx.x & 63;
  const long row = (long)blockIdx.x * 4 + w;
  const float4 v = *(const float4*)(in + row * 256 + l * 4);
  float mx = fmaxf(fmaxf(v.x, v.y), fmaxf(v.z, v.w));
  mx = fmaxf(mx, __shfl_xor(mx, 1, 64));
  mx = fmaxf(mx, __shfl_xor(mx, 2, 64));
  mx = fmaxf(mx, __shfl_xor(mx, 4, 64));
  mx = fmaxf(mx, __shfl_xor(mx, 8, 64));
  mx = fmaxf(mx, __shfl_xor(mx, 16, 64));
  mx = fmaxf(mx, __shfl_xor(mx, 32, 64));
  const float e0 = __expf(v.x - mx), e1 = __expf(v.y - mx);
  const float e2 = __expf(v.z - mx), e3 = __expf(v.w - mx);
  float sm = e0 + e1 + e2 + e3;
  sm += __shfl_xor(sm, 1, 64);
  sm += __shfl_xor(sm, 2, 64);
  sm += __shfl_xor(sm, 4, 64);
  sm += __shfl_xor(sm, 8, 64);
  sm += __shfl_xor(sm, 16, 64);
  sm += __shfl_xor(sm, 32, 64);
  const float inv = 1.0f / sm;
  bf16x4 o = {(bf16)(e0 * inv), (bf16)(e1 * inv), (bf16)(e2 * inv), (bf16)(e3 * inv)};
  *(bf16x4*)(out + row * 256 + l * 4) = o;
}

// ---------------------------------------------------------------------------
// Generic GEMM: C[M][N] = (A[M][K](lda) @ B[N][K]^T + bias)*alpha, C stride ldc.
// 128x64 tile, BK=64, 4 waves, double-buffered LDS with prefetch.
template <typename OutT>
__global__ __launch_bounds__(256, 3) void gemm_bt(
    const bf16* __restrict__ A, const bf16* __restrict__ B,
    const float* __restrict__ bias, OutT* __restrict__ C,
    int M, int N, int K, int lda, int ldc, float alpha) {
  __shared__ bf16 lA[2][128 * 64];
  __shared__ bf16 lB[2][64 * 64];
  const int tid = threadIdx.x;
  const int w = tid >> 6, l = tid & 63;
  const int hi = l >> 4, lo = l & 15;
  const int m0 = blockIdx.y * 128, n0 = blockIdx.x * 64;
  const int wm = w * 32;

  const int sr8 = l >> 3;
  const int sc = (l & 7) * 8;
  const long aRow = (long)(m0 + wm + sr8);
  const long bRow = (long)(n0 + w * 16 + sr8);

  auto stage = [&](int p, int k0) {
#pragma unroll
    for (int j = 0; j < 4; ++j)
      gl_lds16(A + (aRow + 8 * j) * lda + k0 + sc, (char*)lA[p] + (wm + 8 * j) * 128);
#pragma unroll
    for (int j = 0; j < 2; ++j)
      gl_lds16(B + (bRow + 8 * j) * K + k0 + sc, (char*)lB[p] + (w * 16 + 8 * j) * 128);
  };

  f32x4 acc[2][4] = {};
  stage(0, 0);
  __syncthreads();
  const int nt = K >> 6;

  for (int t = 0; t < nt; ++t) {
    const int p = t & 1;
    if (t + 1 < nt) stage(p ^ 1, (t + 1) << 6);
#pragma unroll
    for (int kk = 0; kk < 2; ++kk) {
      bf16x8 af[2], bfr[4];
#pragma unroll
      for (int mi = 0; mi < 2; ++mi)
        af[mi] = *(const bf16x8*)((const char*)lA[p] + (wm + mi * 16 + lo) * 128 + kk * 64 + hi * 16);
#pragma unroll
      for (int ni = 0; ni < 4; ++ni)
        bfr[ni] = *(const bf16x8*)((const char*)lB[p] + (ni * 16 + lo) * 128 + kk * 64 + hi * 16);
      __builtin_amdgcn_s_setprio(1);
#pragma unroll
      for (int mi = 0; mi < 2; ++mi)
#pragma unroll
        for (int ni = 0; ni < 4; ++ni)
          acc[mi][ni] = MFMA16(af[mi], bfr[ni], acc[mi][ni]);
      __builtin_amdgcn_s_setprio(0);
    }
    __syncthreads();
  }

#pragma unroll
  for (int ni = 0; ni < 4; ++ni) {
    const int col = n0 + ni * 16 + lo;
    const float bv = bias ? bias[col] : 0.0f;
#pragma unroll
    for (int mi = 0; mi < 2; ++mi) {
      const int mrow = m0 + wm + mi * 16 + hi * 4;
#pragma unroll
      for (int r = 0; r < 4; ++r) {
        const long row = mrow + r;
        C[row * (long)ldc + col] = (OutT)((acc[mi][ni][r] + bv) * alpha);
      }
    }
  }
}

// Fused QKV projection, m97 128x128 structure.
__global__ __launch_bounds__(256, 3) void gemm_qkv(
    const bf16* __restrict__ A, const bf16* __restrict__ B,
    const float* __restrict__ bias, bf16* __restrict__ Qo,
    bf16* __restrict__ Ko, bf16* __restrict__ Vto) {
  const int K = 1024;
  __shared__ bf16 lA[128 * 64];
  __shared__ bf16 lB[128 * 64];
  const int tid = threadIdx.x;
  const int w = tid >> 6, l = tid & 63;
  const int hi = l >> 4, lo = l & 15;
  const int m0 = blockIdx.y * 128, n0 = blockIdx.x * 128;
  const int wm = (w >> 1) * 64, wn = (w & 1) * 64;

  const int sr = w * 32 + (l >> 3);
  const int sc = (l & 7) * 8;
  const long aBase = (long)(m0 + sr) * K + sc;
  const long bBase = (long)(n0 + sr) * K + sc;

  f32x4 acc[4][4] = {};

  for (int k0 = 0; k0 < K; k0 += 64) {
#pragma unroll
    for (int j = 0; j < 4; ++j) {
      gl_lds16(A + aBase + (long)8 * j * K + k0, (char*)lA + (w * 32 + 8 * j) * 128);
      gl_lds16(B + bBase + (long)8 * j * K + k0, (char*)lB + (w * 32 + 8 * j) * 128);
    }
    __syncthreads();
#pragma unroll
    for (int kk = 0; kk < 2; ++kk) {
      bf16x8 af[4], bfr[4];
#pragma unroll
      for (int i = 0; i < 4; ++i) {
        af[i]  = *(const bf16x8*)((const char*)lA + (wm + i * 16 + lo) * 128 + kk * 64 + hi * 16);
        bfr[i] = *(const bf16x8*)((const char*)lB + (wn + i * 16 + lo) * 128 + kk * 64 + hi * 16);
      }
#pragma unroll
      for (int mi = 0; mi < 4; ++mi)
#pragma unroll
        for (int ni = 0; ni < 4; ++ni)
          acc[mi][ni] = MFMA16(af[mi], bfr[ni], acc[mi][ni]);
    }
    __syncthreads();
  }

  const int region = n0 >> 10;
#pragma unroll
  for (int ni = 0; ni < 4; ++ni) {
    const int col = n0 + wn + ni * 16 + lo;
    const float bv = bias[col];
#pragma unroll
    for (int mi = 0; mi < 4; ++mi) {
      const int mrow = m0 + wm + mi * 16 + hi * 4;
#pragma unroll
      for (int r = 0; r < 4; ++r) {
        const long row = mrow + r;
        const float v = acc[mi][ni][r] + bv;
        if (region == 0) {
          Qo[row * 1024 + col] = (bf16)v;
        } else if (region == 1) {
          Ko[row * 1024 + (col - 1024)] = (bf16)v;
        } else {
          const long bb = row >> 11, ss = row & 2047;
          Vto[(bb * 1024 + (col - 2048)) * 2048 + ss] = (bf16)v;
        }
      }
    }
  }
}

// ---------------------------------------------------------------------------
// Flash attention, swapped-QK^T 32x32, KEY-SPLIT x4, mask in registers.
// grid 2048 (1-D, XCD-swizzled): role = qt + 16*head + 256*(b*4+quarter).
// LDS exactly 32768 B -> 5 blocks/CU; VGPR forced <=64.
__global__ __launch_bounds__(256, 8) void attn_fwd(
    const bf16* __restrict__ Q, const bf16* __restrict__ Km,
    const bf16* __restrict__ Vt, const float* __restrict__ M2,
    bf16* __restrict__ Opart, float* __restrict__ ml) {
  __shared__ bf16 lK[2][64 * 64];
  __shared__ bf16 lV[2][64 * 64];
  const int lin = blockIdx.x;
  const int role = ((lin & 7) << 8) | (lin >> 3);   // 2048/8 = 256 per XCD
  const int qt = role & 15, hh = (role >> 4) & 15, zz = role >> 8;
  const int b = zz >> 2, quarter = zz & 3;
  const int q0 = qt * 128, kbase = quarter * 512;
  const int tid = threadIdx.x, w = tid >> 6, l = tid & 63;
  const int q31 = l & 31, h32 = l >> 5;
  const long S = 2048, H = 1024;
  const float SCALE2 = 0.125f * 1.44269504f;

  bf16x8 qf[4];
  const long qrow = (long)b * S + q0 + w * 32 + q31;
#pragma unroll
  for (int sl = 0; sl < 4; ++sl)
    qf[sl] = *(const bf16x8*)(Q + qrow * H + hh * 64 + sl * 16 + h32 * 8);

  f32x16 o0 = {}, o1 = {};
  float mrun = -1e30f, lrun = 0.0f;

  const int swr = w * 16 + (l >> 3);
  const int swc = ((l & 7) ^ (l >> 3)) * 8;

  auto stage = [&](int p, int k0) {
#pragma unroll
    for (int j = 0; j < 2; ++j) {
      gl_lds16(Km + ((long)b * S + k0 + swr + 8 * j) * H + hh * 64 + swc,
               (char*)lK[p] + (w * 16 + 8 * j) * 128);
      gl_lds16(Vt + ((long)b * H + hh * 64 + swr + 8 * j) * S + k0 + swc,
               (char*)lV[p] + (w * 16 + 8 * j) * 128);
    }
  };

  stage(0, kbase);
  __syncthreads();

  for (int t = 0; t < 8; ++t) {
    const int p = t & 1, k0 = kbase + t * 64;
    if (t < 7) stage(p ^ 1, k0 + 64);

    // mask rows for this lane (broadcast loads, L1-resident)
    f32x4 mk0[4], mk1[4];
#pragma unroll
    for (int g = 0; g < 4; ++g) {
      mk0[g] = *(const f32x4*)(M2 + (long)b * S + k0 + 8 * g + 4 * h32);
      mk1[g] = *(const f32x4*)(M2 + (long)b * S + k0 + 32 + 8 * g + 4 * h32);
    }

    // S = K Q^T (swapped): D[key][q], q = lane&31
    f32x16 s0 = {}, s1 = {};
    __builtin_amdgcn_s_setprio(1);
#pragma unroll
    for (int sl = 0; sl < 4; ++sl) {
      const int ch = sl * 2 + h32;
      const int cx = (ch ^ (q31 & 7)) * 16;
      const bf16x8 k0f = *(const bf16x8*)((const char*)lK[p] + q31 * 128 + cx);
      const bf16x8 k1f = *(const bf16x8*)((const char*)lK[p] + (32 + q31) * 128 + cx);
      s0 = MFMA32(k0f, qf[sl], s0);
      s1 = MFMA32(k1f, qf[sl], s1);
    }
    __builtin_amdgcn_s_setprio(0);

#pragma unroll
    for (int g = 0; g < 4; ++g)
#pragma unroll
      for (int r = 0; r < 4; ++r) {
        s0[4 * g + r] = s0[4 * g + r] * SCALE2 + mk0[g][r];
        s1[4 * g + r] = s1[4 * g + r] * SCALE2 + mk1[g][r];
      }

    // row max: in-lane tree + one cross-half shuffle
    f32x16 tm;
#pragma unroll
    for (int i = 0; i < 16; ++i) tm[i] = fmaxf(s0[i], s1[i]);
#pragma unroll
    for (int i = 0; i < 8; ++i) tm[i] = fmaxf(tm[i], tm[i + 8]);
#pragma unroll
    for (int i = 0; i < 4; ++i) tm[i] = fmaxf(tm[i], tm[i + 4]);
    float mx = fmaxf(fmaxf(tm[0], tm[1]), fmaxf(tm[2], tm[3]));
    mx = fmaxf(mx, __shfl_xor(mx, 32, 64));

    // defer-max (T13)
    if (__any(mx > mrun + 8.0f)) {
      const float mn = fmaxf(mrun, mx);
      const float f = __builtin_amdgcn_exp2f(mrun - mn);
      mrun = mn;
      lrun *= f;
      float fb[16];
#pragma unroll
      for (int reg = 0; reg < 16; ++reg)
        fb[reg] = __shfl(f, (reg & 3) + 8 * (reg >> 2) + 4 * h32, 64);
#pragma unroll
      for (int reg = 0; reg < 16; ++reg) { o0[reg] *= fb[reg]; o1[reg] *= fb[reg]; }
    }

#pragma unroll
    for (int i = 0; i < 16; ++i) s0[i] = __builtin_amdgcn_exp2f(s0[i] - mrun);
#pragma unroll
    for (int i = 0; i < 16; ++i) s1[i] = __builtin_amdgcn_exp2f(s1[i] - mrun);

    // row sum
    f32x16 ts;
#pragma unroll
    for (int i = 0; i < 16; ++i) ts[i] = s0[i] + s1[i];
#pragma unroll
    for (int i = 0; i < 8; ++i) ts[i] += ts[i + 8];
#pragma unroll
    for (int i = 0; i < 4; ++i) ts[i] += ts[i + 4];
    float rs = (ts[0] + ts[1]) + (ts[2] + ts[3]);
    rs += __shfl_xor(rs, 32, 64);
    lrun += rs;

    // P -> PV A-frags: cvt_pk + permlane32_swap (T12)
    bf16x8 pa[4];
#pragma unroll
    for (int ks = 0; ks < 4; ++ks) {
      const int rb = (ks & 1) * 8;
      unsigned a0, a1, b0, b1;
      if (ks < 2) {
        a0 = cvtpk_bf16(s0[rb + 0], s0[rb + 1]);
        a1 = cvtpk_bf16(s0[rb + 2], s0[rb + 3]);
        b0 = cvtpk_bf16(s0[rb + 4], s0[rb + 5]);
        b1 = cvtpk_bf16(s0[rb + 6], s0[rb + 7]);
      } else {
        a0 = cvtpk_bf16(s1[rb + 0], s1[rb + 1]);
        a1 = cvtpk_bf16(s1[rb + 2], s1[rb + 3]);
        b0 = cvtpk_bf16(s1[rb + 4], s1[rb + 5]);
        b1 = cvtpk_bf16(s1[rb + 6], s1[rb + 7]);
      }
      const u32x2 r02 = __builtin_amdgcn_permlane32_swap(a0, b0, false, false);
      const u32x2 r13 = __builtin_amdgcn_permlane32_swap(a1, b1, false, false);
      const u32x4 pw = {r02[0], r13[0], r02[1], r13[1]};
      pa[ks] = __builtin_bit_cast(bf16x8, pw);
    }

    // O += P V
    __builtin_amdgcn_s_setprio(1);
#pragma unroll
    for (int ks = 0; ks < 4; ++ks) {
      const int ch = ks * 2 + h32;
      const int cx = (ch ^ (q31 & 7)) * 16;
      const bf16x8 v0 = *(const bf16x8*)((const char*)lV[p] + q31 * 128 + cx);
      const bf16x8 v1 = *(const bf16x8*)((const char*)lV[p] + (32 + q31) * 128 + cx);
      o0 = MFMA32(pa[ks], v0, o0);
      o1 = MFMA32(pa[ks], v1, o1);
    }
    __builtin_amdgcn_s_setprio(0);
    __syncthreads();
  }

  // epilogue: unnormalized O + (m,l) per (q,head,quarter)
  if (h32 == 0) {
    float2 v = {mrun, lrun};
    ((float2*)ml)[((long)quarter * 4096 + (long)b * 2048 + q0 + w * 32 + q31) * 16 + hh] = v;
  }
#pragma unroll
  for (int reg = 0; reg < 16; ++reg) {
    const int row = (reg & 3) + 8 * (reg >> 2) + 4 * h32;
    const long qg = (long)b * 2048 + q0 + w * 32 + row;
    Opart[((long)quarter * 4096 + qg) * 1024 + hh * 64 + q31]      = (bf16)o0[reg];
    Opart[((long)quarter * 4096 + qg) * 1024 + hh * 64 + 32 + q31] = (bf16)o1[reg];
  }
}

// Combine 4 key-quarter partials -> CAT left half (stride 1536)
__global__ __launch_bounds__(256) void attn_combine(
    const bf16* __restrict__ Opart, const float* __restrict__ ml,
    bf16* __restrict__ CAT) {
  const long i = ((long)blockIdx.x * 256 + threadIdx.x) * 4;
  const long qg = i >> 10;
  const int h = (int)((i & 1023) >> 6);
  float2 a[4];
#pragma unroll
  for (int j = 0; j < 4; ++j) a[j] = ((const float2*)ml)[((long)j * 4096 + qg) * 16 + h];
  const float m = fmaxf(fmaxf(a[0].x, a[1].x), fmaxf(a[2].x, a[3].x));
  float wgt[4], den = 0.0f;
#pragma unroll
  for (int j = 0; j < 4; ++j) { wgt[j] = __builtin_amdgcn_exp2f(a[j].x - m); den += wgt[j] * a[j].y; }
  const float inv = 1.0f / den;
  float acc[4] = {};
#pragma unroll
  for (int j = 0; j < 4; ++j) {
    const bf16x4 O = *(const bf16x4*)(Opart + (long)j * 4096 * 1024 + i);
#pragma unroll
    for (int e = 0; e < 4; ++e) acc[e] += (float)O[e] * wgt[j];
  }
  const long row = i >> 10, col = i & 1023;
  bf16x4 o;
#pragma unroll
  for (int e = 0; e < 4; ++e) o[e] = (bf16)(acc[e] * inv);
  *(bf16x4*)(CAT + row * 1536 + col) = o;
}

// ---------------------------------------------------------------------------
extern "C" void kernel_launch(void* const* d_in, const int* in_sizes, int n_in,
                              void* d_out, int out_size, void* d_ws, size_t ws_size,
                              hipStream_t stream) {
  const float* X    = (const float*)d_in[0];
  const float* mask = (const float*)d_in[1];
  const float* Wq   = (const float*)d_in[2];  const float* bq  = (const float*)d_in[3];
  const float* Wk   = (const float*)d_in[4];  const float* bk  = (const float*)d_in[5];
  const float* Wv   = (const float*)d_in[6];  const float* bv  = (const float*)d_in[7];
  const float* Wo   = (const float*)d_in[8];  const float* bo  = (const float*)d_in[9];
  const float* mv   = (const float*)d_in[10];
  const float* Wmp  = (const float*)d_in[11]; const float* bmp = (const float*)d_in[12];
  const float* Wma  = (const float*)d_in[13]; const float* bma = (const float*)d_in[14];

  char* ws = (char*)d_ws;
  size_t off = 0;
  auto alloc = [&](size_t bytes) -> void* {
    void* p = ws + off;
    off += (bytes + 255) & ~(size_t)255;
    return p;
  };
  const long MS_ = 4096;
  bf16* Xb    = (bf16*)alloc(MS_ * 1024 * 2);
  bf16* Wqkvb = (bf16*)alloc(3072L * 1024 * 2);
  bf16* WCAT  = (bf16*)alloc(1024L * 1536 * 2);   // [Wo | 0.3*Wo@Wmp]
  bf16* Wmab  = (bf16*)alloc(256 * 1024 * 2);
  bf16* WmpT  = (bf16*)alloc(512L * 1024 * 2);
  bf16* mvTb  = (bf16*)alloc(512 * 256 * 2);
  float* M2   = (float*)alloc(MS_ * 4);
  float* bqkv = (float*)alloc(3072 * 4);
  float* bmix = (float*)alloc(1024 * 4);
  bf16* Qb    = (bf16*)alloc(MS_ * 1024 * 2);
  bf16* Kb    = (bf16*)alloc(MS_ * 1024 * 2);
  bf16* Vtb   = (bf16*)alloc(MS_ * 1024 * 2);
  bf16* CAT   = (bf16*)alloc(MS_ * 1536 * 2);     // [AO | MO]
  char* region = (char*)alloc(4 * MS_ * 1024 * 2 + 4 * MS_ * 16 * 8 + 1024);
  bf16* Opart = (bf16*)region;                               // 32MB
  float* ml   = (float*)(region + 4 * MS_ * 1024 * 2);       // 2MB
  float* MSc  = (float*)region;                              // aliased after combine
  bf16* MP    = (bf16*)(region + MS_ * 256 * 4);

  // 1: prep (converts, WCAT-left, WmpT, M2, bqkv, mvT, bmix)
  fused_prep<<<9483, 256, 0, stream>>>(X, Wq, Wk, Wv, Wo, Wma, Wmp, mask,
                                       bq, bk, bv, mv, bo, bmp,
                                       Xb, Wqkvb, WCAT, Wmab, WmpT, M2, bqkv, mvTb, bmix);
  // 2: Wmix = 0.3 * Wo @ Wmp -> WCAT right half
  gemm_bt<bf16><<<dim3(8, 8), 256, 0, stream>>>(WCAT, WmpT, nullptr, WCAT + 1024,
                                                1024, 512, 1024, 1536, 1536, 0.3f);
  // 3: fused QKV projection (V written transposed)
  gemm_qkv<<<dim3(24, 32), 256, 0, stream>>>(Xb, Wqkvb, bqkv, Qb, Kb, Vtb);
  // 4: attention, key-split x4 (XCD-swizzled 1-D grid) + combine into CAT
  attn_fwd<<<2048, 256, 0, stream>>>(Qb, Kb, Vtb, M2, Opart, ml);
  attn_combine<<<4096, 256, 0, stream>>>(Opart, ml, CAT);
  // 5-7: memory path (MO -> CAT right half)
  gemm_bt<float><<<dim3(4, 32), 256, 0, stream>>>(Xb, Wmab, bma, MSc,
                                                  4096, 256, 1024, 1024, 256, 1.0f);
  softmax_rows256<<<1024, 256, 0, stream>>>(MSc, MP);
  gemm_bt<bf16><<<dim3(8, 32), 256, 0, stream>>>(MP, mvTb, nullptr, CAT + 1024,
                                                 4096, 512, 256, 256, 1536, 1.0f);
  // 8: single fused output projection: [AO|MO] @ [Wo|Wmix]^T + bmix -> fp32 out
  gemm_bt<float><<<dim3(16, 32), 256, 0, stream>>>(CAT, WCAT, bmix, (float*)d_out,
                                                   4096, 1024, 1536, 1536, 1024, 1.0f);
}

// Round 6
// 158.348 us; speedup vs baseline: 1.3473x; 1.3473x over previous
//
#include <hip/hip_runtime.h>

typedef __bf16 bf16;
typedef __bf16 bf16x8 __attribute__((ext_vector_type(8)));
typedef __bf16 bf16x4 __attribute__((ext_vector_type(4)));
typedef float  f32x4  __attribute__((ext_vector_type(4)));
typedef float  f32x16 __attribute__((ext_vector_type(16)));
typedef unsigned u32x2 __attribute__((ext_vector_type(2)));
typedef unsigned u32x4 __attribute__((ext_vector_type(4)));
typedef unsigned long long uptr;

#define MFMA16(a, b, c) __builtin_amdgcn_mfma_f32_16x16x32_bf16((a), (b), (c), 0, 0, 0)
#define MFMA32(a, b, c) __builtin_amdgcn_mfma_f32_32x32x16_bf16((a), (b), (c), 0, 0, 0)

__device__ __forceinline__ void gl_lds16(const void* g, void* l) {
  __builtin_amdgcn_global_load_lds(
      (__attribute__((address_space(1))) void*)(uptr)(g),
      (__attribute__((address_space(3))) void*)(uptr)(l),
      16, 0, 0);
}
__device__ __forceinline__ void gl_lds4(const void* g, void* l) {
  __builtin_amdgcn_global_load_lds(
      (__attribute__((address_space(1))) void*)(uptr)(g),
      (__attribute__((address_space(3))) void*)(uptr)(l),
      4, 0, 0);
}
__device__ __forceinline__ unsigned cvtpk_bf16(float lo, float hi) {
  unsigned r;
  asm("v_cvt_pk_bf16_f32 %0, %1, %2" : "=v"(r) : "v"(lo), "v"(hi));
  return r;
}

// ---------------------------------------------------------------------------
// Fused prep. NOTE: Wq and bq are PRE-SCALED by 0.125*log2(e) so the QK^T
// MFMA output is already in exp2-score domain (scale pass eliminated in attn).
__global__ __launch_bounds__(256) void fused_prep(
    const float* __restrict__ X, const float* __restrict__ Wq,
    const float* __restrict__ Wk, const float* __restrict__ Wv,
    const float* __restrict__ Wo, const float* __restrict__ Wma,
    const float* __restrict__ Wmp, const float* __restrict__ mask,
    const float* __restrict__ bq, const float* __restrict__ bk,
    const float* __restrict__ bv, const float* __restrict__ mv,
    bf16* __restrict__ Xb, bf16* __restrict__ Wqkvb, bf16* __restrict__ Wob,
    bf16* __restrict__ Wmab, bf16* __restrict__ Wmpb,
    float* __restrict__ M2, float* __restrict__ bqkv, bf16* __restrict__ mvTb) {
  const int bid = blockIdx.x, t = threadIdx.x;
  const float QS = 0.125f * 1.44269504f;
  auto cvt = [&](const float* src, bf16* dst, int blk, float sc) {
    const long i = ((long)blk * 256 + t) * 4;
    const float4 v = *(const float4*)(src + i);
    bf16x4 o = {(bf16)(v.x * sc), (bf16)(v.y * sc), (bf16)(v.z * sc), (bf16)(v.w * sc)};
    *(bf16x4*)(dst + i) = o;
  };
  if (bid < 4096) cvt(X, Xb, bid, 1.0f);
  else if (bid < 5120) cvt(Wq, Wqkvb, bid - 4096, QS);          // scaled Q weights
  else if (bid < 6144) cvt(Wk, Wqkvb + 1024 * 1024, bid - 5120, 1.0f);
  else if (bid < 7168) cvt(Wv, Wqkvb + 2 * 1024 * 1024, bid - 6144, 1.0f);
  else if (bid < 8192) cvt(Wo, Wob, bid - 7168, 1.0f);
  else if (bid < 8448) cvt(Wma, Wmab, bid - 8192, 1.0f);
  else if (bid < 8960) cvt(Wmp, Wmpb, bid - 8448, 1.0f);
  else if (bid < 8964) {  // mask -> exp2-domain additive
    const long i = ((long)(bid - 8960) * 256 + t) * 4;
    const float4 v = *(const float4*)(mask + i);
    float4 o = {v.x * -1.44269504e9f, v.y * -1.44269504e9f,
                v.z * -1.44269504e9f, v.w * -1.44269504e9f};
    *(float4*)(M2 + i) = o;
  } else if (bid < 8967) {  // bias concat (bq scaled)
    const int s = bid - 8964;
    const float* src = s == 0 ? bq : (s == 1 ? bk : bv);
    const float sc = s == 0 ? QS : 1.0f;
    float4 v = *(const float4*)(src + t * 4);
    float4 o = {v.x * sc, v.y * sc, v.z * sc, v.w * sc};
    *(float4*)(bqkv + s * 1024 + t * 4) = o;
  } else {  // memory_values transpose [256][512] -> [512][256] bf16
    const int d = bid - 8967;
    mvTb[(long)d * 256 + t] = (bf16)mv[(long)t * 512 + d];
  }
}

// row softmax over 256 cols, fp32 in, bf16 out. one wave per row.
__global__ __launch_bounds__(256) void softmax_rows256(const float* __restrict__ in,
                                                       bf16* __restrict__ out) {
  const int w = threadIdx.x >> 6, l = threadIdx.x & 63;
  const long row = (long)blockIdx.x * 4 + w;
  const float4 v = *(const float4*)(in + row * 256 + l * 4);
  float mx = fmaxf(fmaxf(v.x, v.y), fmaxf(v.z, v.w));
  mx = fmaxf(mx, __shfl_xor(mx, 1, 64));
  mx = fmaxf(mx, __shfl_xor(mx, 2, 64));
  mx = fmaxf(mx, __shfl_xor(mx, 4, 64));
  mx = fmaxf(mx, __shfl_xor(mx, 8, 64));
  mx = fmaxf(mx, __shfl_xor(mx, 16, 64));
  mx = fmaxf(mx, __shfl_xor(mx, 32, 64));
  const float e0 = __expf(v.x - mx), e1 = __expf(v.y - mx);
  const float e2 = __expf(v.z - mx), e3 = __expf(v.w - mx);
  float sm = e0 + e1 + e2 + e3;
  sm += __shfl_xor(sm, 1, 64);
  sm += __shfl_xor(sm, 2, 64);
  sm += __shfl_xor(sm, 4, 64);
  sm += __shfl_xor(sm, 8, 64);
  sm += __shfl_xor(sm, 16, 64);
  sm += __shfl_xor(sm, 32, 64);
  const float inv = 1.0f / sm;
  bf16x4 o = {(bf16)(e0 * inv), (bf16)(e1 * inv), (bf16)(e2 * inv), (bf16)(e3 * inv)};
  *(bf16x4*)(out + row * 256 + l * 4) = o;
}

// ---------------------------------------------------------------------------
// Generic GEMM: C[M][N] = (A[M][K] @ B[N][K]^T + bias)*alpha (+ add)
// 128x64 tile, BK=64, 4 waves, double-buffered LDS with prefetch.
template <typename OutT, bool HAS_ADD>
__global__ __launch_bounds__(256, 3) void gemm_bt(
    const bf16* __restrict__ A, const bf16* __restrict__ B,
    const float* __restrict__ bias, const bf16* __restrict__ addsrc,
    OutT* __restrict__ C, int M, int N, int K, float alpha) {
  __shared__ bf16 lA[2][128 * 64];
  __shared__ bf16 lB[2][64 * 64];
  const int tid = threadIdx.x;
  const int w = tid >> 6, l = tid & 63;
  const int hi = l >> 4, lo = l & 15;
  const int m0 = blockIdx.y * 128, n0 = blockIdx.x * 64;
  const int wm = w * 32;

  const int sr8 = l >> 3;
  const int sc = (l & 7) * 8;
  const long aRow = (long)(m0 + wm + sr8);
  const long bRow = (long)(n0 + w * 16 + sr8);

  auto stage = [&](int p, int k0) {
#pragma unroll
    for (int j = 0; j < 4; ++j)
      gl_lds16(A + (aRow + 8 * j) * K + k0 + sc, (char*)lA[p] + (wm + 8 * j) * 128);
#pragma unroll
    for (int j = 0; j < 2; ++j)
      gl_lds16(B + (bRow + 8 * j) * K + k0 + sc, (char*)lB[p] + (w * 16 + 8 * j) * 128);
  };

  f32x4 acc[2][4] = {};
  stage(0, 0);
  __syncthreads();
  const int nt = K >> 6;

  for (int t = 0; t < nt; ++t) {
    const int p = t & 1;
    if (t + 1 < nt) stage(p ^ 1, (t + 1) << 6);
#pragma unroll
    for (int kk = 0; kk < 2; ++kk) {
      bf16x8 af[2], bfr[4];
#pragma unroll
      for (int mi = 0; mi < 2; ++mi)
        af[mi] = *(const bf16x8*)((const char*)lA[p] + (wm + mi * 16 + lo) * 128 + kk * 64 + hi * 16);
#pragma unroll
      for (int ni = 0; ni < 4; ++ni)
        bfr[ni] = *(const bf16x8*)((const char*)lB[p] + (ni * 16 + lo) * 128 + kk * 64 + hi * 16);
      __builtin_amdgcn_s_setprio(1);
#pragma unroll
      for (int mi = 0; mi < 2; ++mi)
#pragma unroll
        for (int ni = 0; ni < 4; ++ni)
          acc[mi][ni] = MFMA16(af[mi], bfr[ni], acc[mi][ni]);
      __builtin_amdgcn_s_setprio(0);
    }
    __syncthreads();
  }

#pragma unroll
  for (int ni = 0; ni < 4; ++ni) {
    const int col = n0 + ni * 16 + lo;
    const float bv = bias ? bias[col] : 0.0f;
#pragma unroll
    for (int mi = 0; mi < 2; ++mi) {
      const int mrow = m0 + wm + mi * 16 + hi * 4;
#pragma unroll
      for (int r = 0; r < 4; ++r) {
        const long row = mrow + r;
        float v = (acc[mi][ni][r] + bv) * alpha;
        if (HAS_ADD) v += (float)addsrc[row * N + col];
        C[row * (long)N + col] = (OutT)v;
      }
    }
  }
}

// Fused QKV projection, m97 128x128 structure.
__global__ __launch_bounds__(256, 3) void gemm_qkv(
    const bf16* __restrict__ A, const bf16* __restrict__ B,
    const float* __restrict__ bias, bf16* __restrict__ Qo,
    bf16* __restrict__ Ko, bf16* __restrict__ Vto) {
  const int K = 1024;
  __shared__ bf16 lA[128 * 64];
  __shared__ bf16 lB[128 * 64];
  const int tid = threadIdx.x;
  const int w = tid >> 6, l = tid & 63;
  const int hi = l >> 4, lo = l & 15;
  const int m0 = blockIdx.y * 128, n0 = blockIdx.x * 128;
  const int wm = (w >> 1) * 64, wn = (w & 1) * 64;

  const int sr = w * 32 + (l >> 3);
  const int sc = (l & 7) * 8;
  const long aBase = (long)(m0 + sr) * K + sc;
  const long bBase = (long)(n0 + sr) * K + sc;

  f32x4 acc[4][4] = {};

  for (int k0 = 0; k0 < K; k0 += 64) {
#pragma unroll
    for (int j = 0; j < 4; ++j) {
      gl_lds16(A + aBase + (long)8 * j * K + k0, (char*)lA + (w * 32 + 8 * j) * 128);
      gl_lds16(B + bBase + (long)8 * j * K + k0, (char*)lB + (w * 32 + 8 * j) * 128);
    }
    __syncthreads();
#pragma unroll
    for (int kk = 0; kk < 2; ++kk) {
      bf16x8 af[4], bfr[4];
#pragma unroll
      for (int i = 0; i < 4; ++i) {
        af[i]  = *(const bf16x8*)((const char*)lA + (wm + i * 16 + lo) * 128 + kk * 64 + hi * 16);
        bfr[i] = *(const bf16x8*)((const char*)lB + (wn + i * 16 + lo) * 128 + kk * 64 + hi * 16);
      }
#pragma unroll
      for (int mi = 0; mi < 4; ++mi)
#pragma unroll
        for (int ni = 0; ni < 4; ++ni)
          acc[mi][ni] = MFMA16(af[mi], bfr[ni], acc[mi][ni]);
    }
    __syncthreads();
  }

  const int region = n0 >> 10;
#pragma unroll
  for (int ni = 0; ni < 4; ++ni) {
    const int col = n0 + wn + ni * 16 + lo;
    const float bv = bias[col];
#pragma unroll
    for (int mi = 0; mi < 4; ++mi) {
      const int mrow = m0 + wm + mi * 16 + hi * 4;
#pragma unroll
      for (int r = 0; r < 4; ++r) {
        const long row = mrow + r;
        const float v = acc[mi][ni][r] + bv;
        if (region == 0) {
          Qo[row * 1024 + col] = (bf16)v;
        } else if (region == 1) {
          Ko[row * 1024 + (col - 1024)] = (bf16)v;
        } else {
          const long bb = row >> 11, ss = row & 2047;
          Vto[(bb * 1024 + (col - 2048)) * 2048 + ss] = (bf16)v;
        }
      }
    }
  }
}

// ---------------------------------------------------------------------------
// Flash attention, swapped-QK^T 32x32, KEY-SPLIT x2 (R4 structure).
// Q pre-scaled by 0.125*log2e; QK^T accumulator INITIALIZED with mask (M2) ->
// no per-element scale/mask pass. Row max via v_max3_f32 chain (T17).
__global__ __launch_bounds__(256, 4) void attn_fwd(
    const bf16* __restrict__ Q, const bf16* __restrict__ Km,
    const bf16* __restrict__ Vt, const float* __restrict__ M2,
    bf16* __restrict__ Opart, float* __restrict__ ml) {
  __shared__ bf16 lK[2][64 * 64];
  __shared__ bf16 lV[2][64 * 64];
  __shared__ alignas(16) float lM[2][64];
  const int tid = threadIdx.x, w = tid >> 6, l = tid & 63;
  const int q31 = l & 31, h32 = l >> 5;
  const int b = blockIdx.z >> 1, half = blockIdx.z & 1;
  const int hh = blockIdx.y, q0 = blockIdx.x * 128;
  const long S = 2048, H = 1024;
  const int kbase = half * 1024;

  bf16x8 qf[4];
  const long qrow = (long)b * S + q0 + w * 32 + q31;
#pragma unroll
  for (int sl = 0; sl < 4; ++sl)
    qf[sl] = *(const bf16x8*)(Q + qrow * H + hh * 64 + sl * 16 + h32 * 8);

  f32x16 o0 = {}, o1 = {};
  float mrun = -1e30f, lrun = 0.0f;

  const int swr = w * 16 + (l >> 3);
  const int swc = ((l & 7) ^ (l >> 3)) * 8;

  auto stage = [&](int p, int k0) {
#pragma unroll
    for (int j = 0; j < 2; ++j) {
      gl_lds16(Km + ((long)b * S + k0 + swr + 8 * j) * H + hh * 64 + swc,
               (char*)lK[p] + (w * 16 + 8 * j) * 128);
      gl_lds16(Vt + ((long)b * H + hh * 64 + swr + 8 * j) * S + k0 + swc,
               (char*)lV[p] + (w * 16 + 8 * j) * 128);
    }
    if (w == 0) gl_lds4(M2 + (long)b * S + k0 + l, (char*)lM[p]);
  };

  stage(0, kbase);
  __syncthreads();

  for (int t = 0; t < 16; ++t) {
    const int p = t & 1;
    if (t < 15) stage(p ^ 1, kbase + (t + 1) * 64);

    // init accumulators with mask (exp2-domain additive); reg r -> key row
    // (r&3)+8*(r>>2)+4*h32 within each 32-key half
    f32x16 s0, s1;
#pragma unroll
    for (int g = 0; g < 4; ++g) {
      const f32x4 m0 = *(const f32x4*)&lM[p][8 * g + 4 * h32];
      const f32x4 m1 = *(const f32x4*)&lM[p][32 + 8 * g + 4 * h32];
#pragma unroll
      for (int r = 0; r < 4; ++r) {
        s0[4 * g + r] = m0[r];
        s1[4 * g + r] = m1[r];
      }
    }

    // S = K Q^T (swapped): D[key][q], q = lane&31; already exp2-scaled
    __builtin_amdgcn_s_setprio(1);
#pragma unroll
    for (int sl = 0; sl < 4; ++sl) {
      const int ch = sl * 2 + h32;
      const int cx = (ch ^ (q31 & 7)) * 16;
      const bf16x8 k0f = *(const bf16x8*)((const char*)lK[p] + q31 * 128 + cx);
      const bf16x8 k1f = *(const bf16x8*)((const char*)lK[p] + (32 + q31) * 128 + cx);
      s0 = MFMA32(k0f, qf[sl], s0);
      s1 = MFMA32(k1f, qf[sl], s1);
    }
    __builtin_amdgcn_s_setprio(0);

    // row max: v_max3 chain + one cross-half shuffle
    float mm = -1e30f;
#pragma unroll
    for (int i = 0; i < 16; ++i)
      asm("v_max3_f32 %0, %1, %2, %3" : "=v"(mm) : "v"(mm), "v"(s0[i]), "v"(s1[i]));
    float mx = fmaxf(mm, __shfl_xor(mm, 32, 64));

    // defer-max (T13)
    if (__any(mx > mrun + 8.0f)) {
      const float mn = fmaxf(mrun, mx);
      const float f = __builtin_amdgcn_exp2f(mrun - mn);
      mrun = mn;
      lrun *= f;
      float fb[16];
#pragma unroll
      for (int reg = 0; reg < 16; ++reg)
        fb[reg] = __shfl(f, (reg & 3) + 8 * (reg >> 2) + 4 * h32, 64);
#pragma unroll
      for (int reg = 0; reg < 16; ++reg) { o0[reg] *= fb[reg]; o1[reg] *= fb[reg]; }
    }

    // P = exp2(s - m)
#pragma unroll
    for (int i = 0; i < 16; ++i) s0[i] = __builtin_amdgcn_exp2f(s0[i] - mrun);
#pragma unroll
    for (int i = 0; i < 16; ++i) s1[i] = __builtin_amdgcn_exp2f(s1[i] - mrun);

    // row sum: in-lane tree + one cross-half shuffle
    f32x16 ts;
#pragma unroll
    for (int i = 0; i < 16; ++i) ts[i] = s0[i] + s1[i];
#pragma unroll
    for (int i = 0; i < 8; ++i) ts[i] += ts[i + 8];
#pragma unroll
    for (int i = 0; i < 4; ++i) ts[i] += ts[i + 4];
    float rs = (ts[0] + ts[1]) + (ts[2] + ts[3]);
    rs += __shfl_xor(rs, 32, 64);
    lrun += rs;

    // P -> PV A-frags: cvt_pk + permlane32_swap (T12)
    bf16x8 pa[4];
#pragma unroll
    for (int ks = 0; ks < 4; ++ks) {
      const int rb = (ks & 1) * 8;
      unsigned a0, a1, b0, b1;
      if (ks < 2) {
        a0 = cvtpk_bf16(s0[rb + 0], s0[rb + 1]);
        a1 = cvtpk_bf16(s0[rb + 2], s0[rb + 3]);
        b0 = cvtpk_bf16(s0[rb + 4], s0[rb + 5]);
        b1 = cvtpk_bf16(s0[rb + 6], s0[rb + 7]);
      } else {
        a0 = cvtpk_bf16(s1[rb + 0], s1[rb + 1]);
        a1 = cvtpk_bf16(s1[rb + 2], s1[rb + 3]);
        b0 = cvtpk_bf16(s1[rb + 4], s1[rb + 5]);
        b1 = cvtpk_bf16(s1[rb + 6], s1[rb + 7]);
      }
      const u32x2 r02 = __builtin_amdgcn_permlane32_swap(a0, b0, false, false);
      const u32x2 r13 = __builtin_amdgcn_permlane32_swap(a1, b1, false, false);
      const u32x4 pw = {r02[0], r13[0], r02[1], r13[1]};
      pa[ks] = __builtin_bit_cast(bf16x8, pw);
    }

    // O += P V
    __builtin_amdgcn_s_setprio(1);
#pragma unroll
    for (int ks = 0; ks < 4; ++ks) {
      const int ch = ks * 2 + h32;
      const int cx = (ch ^ (q31 & 7)) * 16;
      const bf16x8 v0 = *(const bf16x8*)((const char*)lV[p] + q31 * 128 + cx);
      const bf16x8 v1 = *(const bf16x8*)((const char*)lV[p] + (32 + q31) * 128 + cx);
      o0 = MFMA32(pa[ks], v0, o0);
      o1 = MFMA32(pa[ks], v1, o1);
    }
    __builtin_amdgcn_s_setprio(0);
    __syncthreads();
  }

  // epilogue: unnormalized O + (m,l) per (q,head,half)
  if (h32 == 0) {
    float2 v = {mrun, lrun};
    ((float2*)ml)[((long)half * 4096 + (long)b * 2048 + q0 + w * 32 + q31) * 16 + hh] = v;
  }
#pragma unroll
  for (int reg = 0; reg < 16; ++reg) {
    const int row = (reg & 3) + 8 * (reg >> 2) + 4 * h32;
    const long qg = (long)b * 2048 + q0 + w * 32 + row;
    Opart[((long)half * 4096 + qg) * 1024 + hh * 64 + q31]      = (bf16)o0[reg];
    Opart[((long)half * 4096 + qg) * 1024 + hh * 64 + 32 + q31] = (bf16)o1[reg];
  }
}

// Combine the two key-half partials: AO = (w0*O0 + w1*O1) / (w0*l0 + w1*l1)
__global__ __launch_bounds__(256) void attn_combine(
    const bf16* __restrict__ Opart, const float* __restrict__ ml,
    bf16* __restrict__ AO) {
  const long i = ((long)blockIdx.x * 256 + threadIdx.x) * 4;
  const long qg = i >> 10;
  const int h = (int)((i & 1023) >> 6);
  const float2 a = ((const float2*)ml)[qg * 16 + h];
  const float2 c = ((const float2*)ml)[(4096 + qg) * 16 + h];
  const float m = fmaxf(a.x, c.x);
  const float w0 = __builtin_amdgcn_exp2f(a.x - m);
  const float w1 = __builtin_amdgcn_exp2f(c.x - m);
  const float inv = 1.0f / (w0 * a.y + w1 * c.y);
  const bf16x4 O0 = *(const bf16x4*)(Opart + i);
  const bf16x4 O1 = *(const bf16x4*)(Opart + 4096L * 1024 + i);
  bf16x4 o;
#pragma unroll
  for (int j = 0; j < 4; ++j)
    o[j] = (bf16)(((float)O0[j] * w0 + (float)O1[j] * w1) * inv);
  *(bf16x4*)(AO + i) = o;
}

// ---------------------------------------------------------------------------
extern "C" void kernel_launch(void* const* d_in, const int* in_sizes, int n_in,
                              void* d_out, int out_size, void* d_ws, size_t ws_size,
                              hipStream_t stream) {
  const float* X    = (const float*)d_in[0];
  const float* mask = (const float*)d_in[1];
  const float* Wq   = (const float*)d_in[2];  const float* bq  = (const float*)d_in[3];
  const float* Wk   = (const float*)d_in[4];  const float* bk  = (const float*)d_in[5];
  const float* Wv   = (const float*)d_in[6];  const float* bv  = (const float*)d_in[7];
  const float* Wo   = (const float*)d_in[8];  const float* bo  = (const float*)d_in[9];
  const float* mv   = (const float*)d_in[10];
  const float* Wmp  = (const float*)d_in[11]; const float* bmp = (const float*)d_in[12];
  const float* Wma  = (const float*)d_in[13]; const float* bma = (const float*)d_in[14];

  char* ws = (char*)d_ws;
  size_t off = 0;
  auto alloc = [&](size_t bytes) -> void* {
    void* p = ws + off;
    off += (bytes + 255) & ~(size_t)255;
    return p;
  };
  const long MS_ = 4096;
  bf16* Xb    = (bf16*)alloc(MS_ * 1024 * 2);
  bf16* Wqkvb = (bf16*)alloc(3072L * 1024 * 2);
  bf16* Wob   = (bf16*)alloc(1024 * 1024 * 2);
  bf16* Wmab  = (bf16*)alloc(256 * 1024 * 2);
  bf16* Wmpb  = (bf16*)alloc(1024 * 512 * 2);
  bf16* mvTb  = (bf16*)alloc(512 * 256 * 2);
  float* M2   = (float*)alloc(MS_ * 4);
  float* bqkv = (float*)alloc(3072 * 4);
  bf16* Qb    = (bf16*)alloc(MS_ * 1024 * 2);
  bf16* Kb    = (bf16*)alloc(MS_ * 1024 * 2);
  bf16* Vtb   = (bf16*)alloc(MS_ * 1024 * 2);  // [B][h*64+d][S]
  bf16* AO    = (bf16*)alloc(MS_ * 1024 * 2);
  char* region = (char*)alloc(2 * MS_ * 1024 * 2 + MS_ * 16 * 8 + 1024);
  bf16* Opart = (bf16*)region;                           // [2][4096][1024] bf16 = 16MB
  float* ml   = (float*)(region + 2 * MS_ * 1024 * 2);   // [2][4096][16] float2 = 1MB
  float* MSc  = (float*)region;                          // aliased after combine
  bf16* MP    = (bf16*)(region + MS_ * 256 * 4);
  bf16* MO    = Kb;                                      // dead after attn
  bf16* CB    = Qb;                                      // dead after attn

  // 1: prep (Wq/bq pre-scaled)
  fused_prep<<<9479, 256, 0, stream>>>(X, Wq, Wk, Wv, Wo, Wma, Wmp, mask,
                                       bq, bk, bv, mv,
                                       Xb, Wqkvb, Wob, Wmab, Wmpb, M2, bqkv, mvTb);
  // 2: fused QKV projection, 128x128 m97 tile (V written transposed)
  gemm_qkv<<<dim3(24, 32), 256, 0, stream>>>(Xb, Wqkvb, bqkv, Qb, Kb, Vtb);
  // 3: attention, key-split x2 + combine
  attn_fwd<<<dim3(16, 16, 4), 256, 0, stream>>>(Qb, Kb, Vtb, M2, Opart, ml);
  attn_combine<<<4096, 256, 0, stream>>>(Opart, ml, AO);
  // 4-6: memory path
  gemm_bt<float, false><<<dim3(4, 32), 256, 0, stream>>>(Xb, Wmab, bma, nullptr, MSc, 4096, 256, 1024, 1.0f);
  softmax_rows256<<<1024, 256, 0, stream>>>(MSc, MP);
  gemm_bt<bf16, false><<<dim3(8, 32), 256, 0, stream>>>(MP, mvTb, nullptr, nullptr, MO, 4096, 512, 256, 1.0f);
  // 7: combined = attn_out + 0.3*(mem_out @ Wmp^T + bmp)
  gemm_bt<bf16, true><<<dim3(16, 32), 256, 0, stream>>>(MO, Wmpb, bmp, AO, CB, 4096, 1024, 512, 0.3f);
  // 8: final projection -> fp32 out
  gemm_bt<float, false><<<dim3(16, 32), 256, 0, stream>>>(CB, Wob, bo, nullptr, (float*)d_out, 4096, 1024, 1024, 1.0f);
}

// Round 7
// 153.158 us; speedup vs baseline: 1.3929x; 1.0339x over previous
//
#include <hip/hip_runtime.h>

typedef __bf16 bf16;
typedef __bf16 bf16x8 __attribute__((ext_vector_type(8)));
typedef __bf16 bf16x4 __attribute__((ext_vector_type(4)));
typedef float  f32x4  __attribute__((ext_vector_type(4)));
typedef float  f32x16 __attribute__((ext_vector_type(16)));
typedef unsigned u32x2 __attribute__((ext_vector_type(2)));
typedef unsigned u32x4 __attribute__((ext_vector_type(4)));
typedef unsigned long long uptr;

#define MFMA16(a, b, c) __builtin_amdgcn_mfma_f32_16x16x32_bf16((a), (b), (c), 0, 0, 0)
#define MFMA32(a, b, c) __builtin_amdgcn_mfma_f32_32x32x16_bf16((a), (b), (c), 0, 0, 0)

__device__ __forceinline__ void gl_lds16(const void* g, void* l) {
  __builtin_amdgcn_global_load_lds(
      (__attribute__((address_space(1))) void*)(uptr)(g),
      (__attribute__((address_space(3))) void*)(uptr)(l),
      16, 0, 0);
}
__device__ __forceinline__ void gl_lds4(const void* g, void* l) {
  __builtin_amdgcn_global_load_lds(
      (__attribute__((address_space(1))) void*)(uptr)(g),
      (__attribute__((address_space(3))) void*)(uptr)(l),
      4, 0, 0);
}
__device__ __forceinline__ unsigned cvtpk_bf16(float lo, float hi) {
  unsigned r;
  asm("v_cvt_pk_bf16_f32 %0, %1, %2" : "=v"(r) : "v"(lo), "v"(hi));
  return r;
}

// ---------------------------------------------------------------------------
// Fused prep. NOTE: Wq and bq are PRE-SCALED by 0.125*log2(e) so the QK^T
// MFMA output is already in exp2-score domain (scale pass eliminated in attn).
__global__ __launch_bounds__(256) void fused_prep(
    const float* __restrict__ X, const float* __restrict__ Wq,
    const float* __restrict__ Wk, const float* __restrict__ Wv,
    const float* __restrict__ Wo, const float* __restrict__ Wma,
    const float* __restrict__ Wmp, const float* __restrict__ mask,
    const float* __restrict__ bq, const float* __restrict__ bk,
    const float* __restrict__ bv, const float* __restrict__ mv,
    bf16* __restrict__ Xb, bf16* __restrict__ Wqkvb, bf16* __restrict__ Wob,
    bf16* __restrict__ Wmab, bf16* __restrict__ Wmpb,
    float* __restrict__ M2, float* __restrict__ bqkv, bf16* __restrict__ mvTb) {
  const int bid = blockIdx.x, t = threadIdx.x;
  const float QS = 0.125f * 1.44269504f;
  auto cvt = [&](const float* src, bf16* dst, int blk, float sc) {
    const long i = ((long)blk * 256 + t) * 4;
    const float4 v = *(const float4*)(src + i);
    bf16x4 o = {(bf16)(v.x * sc), (bf16)(v.y * sc), (bf16)(v.z * sc), (bf16)(v.w * sc)};
    *(bf16x4*)(dst + i) = o;
  };
  if (bid < 4096) cvt(X, Xb, bid, 1.0f);
  else if (bid < 5120) cvt(Wq, Wqkvb, bid - 4096, QS);          // scaled Q weights
  else if (bid < 6144) cvt(Wk, Wqkvb + 1024 * 1024, bid - 5120, 1.0f);
  else if (bid < 7168) cvt(Wv, Wqkvb + 2 * 1024 * 1024, bid - 6144, 1.0f);
  else if (bid < 8192) cvt(Wo, Wob, bid - 7168, 1.0f);
  else if (bid < 8448) cvt(Wma, Wmab, bid - 8192, 1.0f);
  else if (bid < 8960) cvt(Wmp, Wmpb, bid - 8448, 1.0f);
  else if (bid < 8964) {  // mask -> exp2-domain additive
    const long i = ((long)(bid - 8960) * 256 + t) * 4;
    const float4 v = *(const float4*)(mask + i);
    float4 o = {v.x * -1.44269504e9f, v.y * -1.44269504e9f,
                v.z * -1.44269504e9f, v.w * -1.44269504e9f};
    *(float4*)(M2 + i) = o;
  } else if (bid < 8967) {  // bias concat (bq scaled)
    const int s = bid - 8964;
    const float* src = s == 0 ? bq : (s == 1 ? bk : bv);
    const float sc = s == 0 ? QS : 1.0f;
    float4 v = *(const float4*)(src + t * 4);
    float4 o = {v.x * sc, v.y * sc, v.z * sc, v.w * sc};
    *(float4*)(bqkv + s * 1024 + t * 4) = o;
  } else {  // memory_values transpose [256][512] -> [512][256] bf16
    const int d = bid - 8967;
    mvTb[(long)d * 256 + t] = (bf16)mv[(long)t * 512 + d];
  }
}

// row softmax over 256 cols, fp32 in, bf16 out. one wave per row.
__global__ __launch_bounds__(256) void softmax_rows256(const float* __restrict__ in,
                                                       bf16* __restrict__ out) {
  const int w = threadIdx.x >> 6, l = threadIdx.x & 63;
  const long row = (long)blockIdx.x * 4 + w;
  const float4 v = *(const float4*)(in + row * 256 + l * 4);
  float mx = fmaxf(fmaxf(v.x, v.y), fmaxf(v.z, v.w));
  mx = fmaxf(mx, __shfl_xor(mx, 1, 64));
  mx = fmaxf(mx, __shfl_xor(mx, 2, 64));
  mx = fmaxf(mx, __shfl_xor(mx, 4, 64));
  mx = fmaxf(mx, __shfl_xor(mx, 8, 64));
  mx = fmaxf(mx, __shfl_xor(mx, 16, 64));
  mx = fmaxf(mx, __shfl_xor(mx, 32, 64));
  const float e0 = __expf(v.x - mx), e1 = __expf(v.y - mx);
  const float e2 = __expf(v.z - mx), e3 = __expf(v.w - mx);
  float sm = e0 + e1 + e2 + e3;
  sm += __shfl_xor(sm, 1, 64);
  sm += __shfl_xor(sm, 2, 64);
  sm += __shfl_xor(sm, 4, 64);
  sm += __shfl_xor(sm, 8, 64);
  sm += __shfl_xor(sm, 16, 64);
  sm += __shfl_xor(sm, 32, 64);
  const float inv = 1.0f / sm;
  bf16x4 o = {(bf16)(e0 * inv), (bf16)(e1 * inv), (bf16)(e2 * inv), (bf16)(e3 * inv)};
  *(bf16x4*)(out + row * 256 + l * 4) = o;
}

// ---------------------------------------------------------------------------
// Generic GEMM: C[M][N] = (A[M][K] @ B[N][K]^T + bias)*alpha (+ add)
// 128x64 tile, BK=64, 4 waves, double-buffered LDS with prefetch.
template <typename OutT, bool HAS_ADD>
__global__ __launch_bounds__(256, 3) void gemm_bt(
    const bf16* __restrict__ A, const bf16* __restrict__ B,
    const float* __restrict__ bias, const bf16* __restrict__ addsrc,
    OutT* __restrict__ C, int M, int N, int K, float alpha) {
  __shared__ bf16 lA[2][128 * 64];
  __shared__ bf16 lB[2][64 * 64];
  const int tid = threadIdx.x;
  const int w = tid >> 6, l = tid & 63;
  const int hi = l >> 4, lo = l & 15;
  const int m0 = blockIdx.y * 128, n0 = blockIdx.x * 64;
  const int wm = w * 32;

  const int sr8 = l >> 3;
  const int sc = (l & 7) * 8;
  const long aRow = (long)(m0 + wm + sr8);
  const long bRow = (long)(n0 + w * 16 + sr8);

  auto stage = [&](int p, int k0) {
#pragma unroll
    for (int j = 0; j < 4; ++j)
      gl_lds16(A + (aRow + 8 * j) * K + k0 + sc, (char*)lA[p] + (wm + 8 * j) * 128);
#pragma unroll
    for (int j = 0; j < 2; ++j)
      gl_lds16(B + (bRow + 8 * j) * K + k0 + sc, (char*)lB[p] + (w * 16 + 8 * j) * 128);
  };

  f32x4 acc[2][4] = {};
  stage(0, 0);
  __syncthreads();
  const int nt = K >> 6;

  for (int t = 0; t < nt; ++t) {
    const int p = t & 1;
    if (t + 1 < nt) stage(p ^ 1, (t + 1) << 6);
#pragma unroll
    for (int kk = 0; kk < 2; ++kk) {
      bf16x8 af[2], bfr[4];
#pragma unroll
      for (int mi = 0; mi < 2; ++mi)
        af[mi] = *(const bf16x8*)((const char*)lA[p] + (wm + mi * 16 + lo) * 128 + kk * 64 + hi * 16);
#pragma unroll
      for (int ni = 0; ni < 4; ++ni)
        bfr[ni] = *(const bf16x8*)((const char*)lB[p] + (ni * 16 + lo) * 128 + kk * 64 + hi * 16);
      __builtin_amdgcn_s_setprio(1);
#pragma unroll
      for (int mi = 0; mi < 2; ++mi)
#pragma unroll
        for (int ni = 0; ni < 4; ++ni)
          acc[mi][ni] = MFMA16(af[mi], bfr[ni], acc[mi][ni]);
      __builtin_amdgcn_s_setprio(0);
    }
    __syncthreads();
  }

#pragma unroll
  for (int ni = 0; ni < 4; ++ni) {
    const int col = n0 + ni * 16 + lo;
    const float bv = bias ? bias[col] : 0.0f;
#pragma unroll
    for (int mi = 0; mi < 2; ++mi) {
      const int mrow = m0 + wm + mi * 16 + hi * 4;
#pragma unroll
      for (int r = 0; r < 4; ++r) {
        const long row = mrow + r;
        float v = (acc[mi][ni][r] + bv) * alpha;
        if (HAS_ADD) v += (float)addsrc[row * N + col];
        C[row * (long)N + col] = (OutT)v;
      }
    }
  }
}

// Fused QKV projection, m97 128x128 structure. V epilogue goes through an
// in-LDS swizzled 128x128 transpose so Vt writes are fully coalesced
// (raw scatter caused 2x write amplification + TA serialization; R6 PMC).
__global__ __launch_bounds__(256, 3) void gemm_qkv(
    const bf16* __restrict__ A, const bf16* __restrict__ B,
    const float* __restrict__ bias, bf16* __restrict__ Qo,
    bf16* __restrict__ Ko, bf16* __restrict__ Vto) {
  const int K = 1024;
  __shared__ bf16 smem[2][128 * 64];   // lA | lB; reused as 128x128 transpose buf
  bf16* lA = smem[0];
  bf16* lB = smem[1];
  const int tid = threadIdx.x;
  const int w = tid >> 6, l = tid & 63;
  const int hi = l >> 4, lo = l & 15;
  const int m0 = blockIdx.y * 128, n0 = blockIdx.x * 128;
  const int wm = (w >> 1) * 64, wn = (w & 1) * 64;

  const int sr = w * 32 + (l >> 3);
  const int sc = (l & 7) * 8;
  const long aBase = (long)(m0 + sr) * K + sc;
  const long bBase = (long)(n0 + sr) * K + sc;

  f32x4 acc[4][4] = {};

  for (int k0 = 0; k0 < K; k0 += 64) {
#pragma unroll
    for (int j = 0; j < 4; ++j) {
      gl_lds16(A + aBase + (long)8 * j * K + k0, (char*)lA + (w * 32 + 8 * j) * 128);
      gl_lds16(B + bBase + (long)8 * j * K + k0, (char*)lB + (w * 32 + 8 * j) * 128);
    }
    __syncthreads();
#pragma unroll
    for (int kk = 0; kk < 2; ++kk) {
      bf16x8 af[4], bfr[4];
#pragma unroll
      for (int i = 0; i < 4; ++i) {
        af[i]  = *(const bf16x8*)((const char*)lA + (wm + i * 16 + lo) * 128 + kk * 64 + hi * 16);
        bfr[i] = *(const bf16x8*)((const char*)lB + (wn + i * 16 + lo) * 128 + kk * 64 + hi * 16);
      }
#pragma unroll
      for (int mi = 0; mi < 4; ++mi)
#pragma unroll
        for (int ni = 0; ni < 4; ++ni)
          acc[mi][ni] = MFMA16(af[mi], bfr[ni], acc[mi][ni]);
    }
    __syncthreads();
  }

  const int region = n0 >> 10;   // 0=Q 1=K 2=V (uniform per block)
  if (region < 2) {
#pragma unroll
    for (int ni = 0; ni < 4; ++ni) {
      const int col = n0 + wn + ni * 16 + lo;
      const float bv = bias[col];
#pragma unroll
      for (int mi = 0; mi < 4; ++mi) {
        const int mrow = m0 + wm + mi * 16 + hi * 4;
#pragma unroll
        for (int r = 0; r < 4; ++r) {
          const long row = mrow + r;
          const float v = acc[mi][ni][r] + bv;
          if (region == 0) Qo[row * 1024 + col] = (bf16)v;
          else             Ko[row * 1024 + (col - 1024)] = (bf16)v;
        }
      }
    }
  } else {
    // V: transpose through LDS. Element (rT, cT) at byte cT*256 + ((2rT)^((cT&15)<<3)).
    bf16* sT = smem[0];
#pragma unroll
    for (int ni = 0; ni < 4; ++ni) {
      const int cT = wn + ni * 16 + lo;
      const float bv = bias[n0 + cT];
#pragma unroll
      for (int mi = 0; mi < 4; ++mi) {
        const int rT = wm + mi * 16 + hi * 4;
        u32x2 pw = {cvtpk_bf16(acc[mi][ni][0] + bv, acc[mi][ni][1] + bv),
                    cvtpk_bf16(acc[mi][ni][2] + bv, acc[mi][ni][3] + bv)};
        *(u32x2*)((char*)sT + cT * 256 + ((rT * 2) ^ ((cT & 15) << 3))) = pw;
      }
    }
    __syncthreads();
    const long vrow0 = (long)(m0 >> 11) * 1024 + (n0 - 2048);
    const int srow = m0 & 2047;
#pragma unroll
    for (int dd = 0; dd < 32; ++dd) {
      const int d = w * 32 + dd;
      const unsigned pv = *(const unsigned*)((const char*)sT + d * 256 + ((l * 4) ^ ((d & 15) << 3)));
      *(unsigned*)((char*)(Vto + (vrow0 + d) * 2048 + srow) + l * 4) = pv;
    }
  }
}

// ---------------------------------------------------------------------------
// Flash attention, swapped-QK^T 32x32, KEY-SPLIT x2.
// Q pre-scaled by 0.125*log2e; QK^T accumulator INITIALIZED with mask (M2) ->
// no per-element scale/mask pass. Row max via v_max3_f32 chain (T17).
__global__ __launch_bounds__(256, 4) void attn_fwd(
    const bf16* __restrict__ Q, const bf16* __restrict__ Km,
    const bf16* __restrict__ Vt, const float* __restrict__ M2,
    bf16* __restrict__ Opart, float* __restrict__ ml) {
  __shared__ bf16 lK[2][64 * 64];
  __shared__ bf16 lV[2][64 * 64];
  __shared__ alignas(16) float lM[2][64];
  const int tid = threadIdx.x, w = tid >> 6, l = tid & 63;
  const int q31 = l & 31, h32 = l >> 5;
  const int b = blockIdx.z >> 1, half = blockIdx.z & 1;
  const int hh = blockIdx.y, q0 = blockIdx.x * 128;
  const long S = 2048, H = 1024;
  const int kbase = half * 1024;

  bf16x8 qf[4];
  const long qrow = (long)b * S + q0 + w * 32 + q31;
#pragma unroll
  for (int sl = 0; sl < 4; ++sl)
    qf[sl] = *(const bf16x8*)(Q + qrow * H + hh * 64 + sl * 16 + h32 * 8);

  f32x16 o0 = {}, o1 = {};
  float mrun = -1e30f, lrun = 0.0f;

  const int swr = w * 16 + (l >> 3);
  const int swc = ((l & 7) ^ (l >> 3)) * 8;

  auto stage = [&](int p, int k0) {
#pragma unroll
    for (int j = 0; j < 2; ++j) {
      gl_lds16(Km + ((long)b * S + k0 + swr + 8 * j) * H + hh * 64 + swc,
               (char*)lK[p] + (w * 16 + 8 * j) * 128);
      gl_lds16(Vt + ((long)b * H + hh * 64 + swr + 8 * j) * S + k0 + swc,
               (char*)lV[p] + (w * 16 + 8 * j) * 128);
    }
    if (w == 0) gl_lds4(M2 + (long)b * S + k0 + l, (char*)lM[p]);
  };

  stage(0, kbase);
  __syncthreads();

  for (int t = 0; t < 16; ++t) {
    const int p = t & 1;
    if (t < 15) stage(p ^ 1, kbase + (t + 1) * 64);

    // init accumulators with mask (exp2-domain additive)
    f32x16 s0, s1;
#pragma unroll
    for (int g = 0; g < 4; ++g) {
      const f32x4 m0 = *(const f32x4*)&lM[p][8 * g + 4 * h32];
      const f32x4 m1 = *(const f32x4*)&lM[p][32 + 8 * g + 4 * h32];
#pragma unroll
      for (int r = 0; r < 4; ++r) {
        s0[4 * g + r] = m0[r];
        s1[4 * g + r] = m1[r];
      }
    }

    // S = K Q^T (swapped): D[key][q], q = lane&31; already exp2-scaled
    __builtin_amdgcn_s_setprio(1);
#pragma unroll
    for (int sl = 0; sl < 4; ++sl) {
      const int ch = sl * 2 + h32;
      const int cx = (ch ^ (q31 & 7)) * 16;
      const bf16x8 k0f = *(const bf16x8*)((const char*)lK[p] + q31 * 128 + cx);
      const bf16x8 k1f = *(const bf16x8*)((const char*)lK[p] + (32 + q31) * 128 + cx);
      s0 = MFMA32(k0f, qf[sl], s0);
      s1 = MFMA32(k1f, qf[sl], s1);
    }
    __builtin_amdgcn_s_setprio(0);

    // row max: v_max3 chain + one cross-half shuffle
    float mm = -1e30f;
#pragma unroll
    for (int i = 0; i < 16; ++i)
      asm("v_max3_f32 %0, %1, %2, %3" : "=v"(mm) : "v"(mm), "v"(s0[i]), "v"(s1[i]));
    float mx = fmaxf(mm, __shfl_xor(mm, 32, 64));

    // defer-max (T13)
    if (__any(mx > mrun + 8.0f)) {
      const float mn = fmaxf(mrun, mx);
      const float f = __builtin_amdgcn_exp2f(mrun - mn);
      mrun = mn;
      lrun *= f;
      float fb[16];
#pragma unroll
      for (int reg = 0; reg < 16; ++reg)
        fb[reg] = __shfl(f, (reg & 3) + 8 * (reg >> 2) + 4 * h32, 64);
#pragma unroll
      for (int reg = 0; reg < 16; ++reg) { o0[reg] *= fb[reg]; o1[reg] *= fb[reg]; }
    }

    // P = exp2(s - m)
#pragma unroll
    for (int i = 0; i < 16; ++i) s0[i] = __builtin_amdgcn_exp2f(s0[i] - mrun);
#pragma unroll
    for (int i = 0; i < 16; ++i) s1[i] = __builtin_amdgcn_exp2f(s1[i] - mrun);

    // row sum: in-lane tree + one cross-half shuffle
    f32x16 ts;
#pragma unroll
    for (int i = 0; i < 16; ++i) ts[i] = s0[i] + s1[i];
#pragma unroll
    for (int i = 0; i < 8; ++i) ts[i] += ts[i + 8];
#pragma unroll
    for (int i = 0; i < 4; ++i) ts[i] += ts[i + 4];
    float rs = (ts[0] + ts[1]) + (ts[2] + ts[3]);
    rs += __shfl_xor(rs, 32, 64);
    lrun += rs;

    // P -> PV A-frags: cvt_pk + permlane32_swap (T12)
    bf16x8 pa[4];
#pragma unroll
    for (int ks = 0; ks < 4; ++ks) {
      const int rb = (ks & 1) * 8;
      unsigned a0, a1, b0, b1;
      if (ks < 2) {
        a0 = cvtpk_bf16(s0[rb + 0], s0[rb + 1]);
        a1 = cvtpk_bf16(s0[rb + 2], s0[rb + 3]);
        b0 = cvtpk_bf16(s0[rb + 4], s0[rb + 5]);
        b1 = cvtpk_bf16(s0[rb + 6], s0[rb + 7]);
      } else {
        a0 = cvtpk_bf16(s1[rb + 0], s1[rb + 1]);
        a1 = cvtpk_bf16(s1[rb + 2], s1[rb + 3]);
        b0 = cvtpk_bf16(s1[rb + 4], s1[rb + 5]);
        b1 = cvtpk_bf16(s1[rb + 6], s1[rb + 7]);
      }
      const u32x2 r02 = __builtin_amdgcn_permlane32_swap(a0, b0, false, false);
      const u32x2 r13 = __builtin_amdgcn_permlane32_swap(a1, b1, false, false);
      const u32x4 pw = {r02[0], r13[0], r02[1], r13[1]};
      pa[ks] = __builtin_bit_cast(bf16x8, pw);
    }

    // O += P V
    __builtin_amdgcn_s_setprio(1);
#pragma unroll
    for (int ks = 0; ks < 4; ++ks) {
      const int ch = ks * 2 + h32;
      const int cx = (ch ^ (q31 & 7)) * 16;
      const bf16x8 v0 = *(const bf16x8*)((const char*)lV[p] + q31 * 128 + cx);
      const bf16x8 v1 = *(const bf16x8*)((const char*)lV[p] + (32 + q31) * 128 + cx);
      o0 = MFMA32(pa[ks], v0, o0);
      o1 = MFMA32(pa[ks], v1, o1);
    }
    __builtin_amdgcn_s_setprio(0);
    __syncthreads();
  }

  // epilogue: unnormalized O + (m,l) per (q,head,half)
  if (h32 == 0) {
    float2 v = {mrun, lrun};
    ((float2*)ml)[((long)half * 4096 + (long)b * 2048 + q0 + w * 32 + q31) * 16 + hh] = v;
  }
#pragma unroll
  for (int reg = 0; reg < 16; ++reg) {
    const int row = (reg & 3) + 8 * (reg >> 2) + 4 * h32;
    const long qg = (long)b * 2048 + q0 + w * 32 + row;
    Opart[((long)half * 4096 + qg) * 1024 + hh * 64 + q31]      = (bf16)o0[reg];
    Opart[((long)half * 4096 + qg) * 1024 + hh * 64 + 32 + q31] = (bf16)o1[reg];
  }
}

// Combine the two key-half partials: AO = (w0*O0 + w1*O1) / (w0*l0 + w1*l1)
__global__ __launch_bounds__(256) void attn_combine(
    const bf16* __restrict__ Opart, const float* __restrict__ ml,
    bf16* __restrict__ AO) {
  const long i = ((long)blockIdx.x * 256 + threadIdx.x) * 4;
  const long qg = i >> 10;
  const int h = (int)((i & 1023) >> 6);
  const float2 a = ((const float2*)ml)[qg * 16 + h];
  const float2 c = ((const float2*)ml)[(4096 + qg) * 16 + h];
  const float m = fmaxf(a.x, c.x);
  const float w0 = __builtin_amdgcn_exp2f(a.x - m);
  const float w1 = __builtin_amdgcn_exp2f(c.x - m);
  const float inv = 1.0f / (w0 * a.y + w1 * c.y);
  const bf16x4 O0 = *(const bf16x4*)(Opart + i);
  const bf16x4 O1 = *(const bf16x4*)(Opart + 4096L * 1024 + i);
  bf16x4 o;
#pragma unroll
  for (int j = 0; j < 4; ++j)
    o[j] = (bf16)(((float)O0[j] * w0 + (float)O1[j] * w1) * inv);
  *(bf16x4*)(AO + i) = o;
}

// ---------------------------------------------------------------------------
extern "C" void kernel_launch(void* const* d_in, const int* in_sizes, int n_in,
                              void* d_out, int out_size, void* d_ws, size_t ws_size,
                              hipStream_t stream) {
  const float* X    = (const float*)d_in[0];
  const float* mask = (const float*)d_in[1];
  const float* Wq   = (const float*)d_in[2];  const float* bq  = (const float*)d_in[3];
  const float* Wk   = (const float*)d_in[4];  const float* bk  = (const float*)d_in[5];
  const float* Wv   = (const float*)d_in[6];  const float* bv  = (const float*)d_in[7];
  const float* Wo   = (const float*)d_in[8];  const float* bo  = (const float*)d_in[9];
  const float* mv   = (const float*)d_in[10];
  const float* Wmp  = (const float*)d_in[11]; const float* bmp = (const float*)d_in[12];
  const float* Wma  = (const float*)d_in[13]; const float* bma = (const float*)d_in[14];

  char* ws = (char*)d_ws;
  size_t off = 0;
  auto alloc = [&](size_t bytes) -> void* {
    void* p = ws + off;
    off += (bytes + 255) & ~(size_t)255;
    return p;
  };
  const long MS_ = 4096;
  bf16* Xb    = (bf16*)alloc(MS_ * 1024 * 2);
  bf16* Wqkvb = (bf16*)alloc(3072L * 1024 * 2);
  bf16* Wob   = (bf16*)alloc(1024 * 1024 * 2);
  bf16* Wmab  = (bf16*)alloc(256 * 1024 * 2);
  bf16* Wmpb  = (bf16*)alloc(1024 * 512 * 2);
  bf16* mvTb  = (bf16*)alloc(512 * 256 * 2);
  float* M2   = (float*)alloc(MS_ * 4);
  float* bqkv = (float*)alloc(3072 * 4);
  bf16* Qb    = (bf16*)alloc(MS_ * 1024 * 2);
  bf16* Kb    = (bf16*)alloc(MS_ * 1024 * 2);
  bf16* Vtb   = (bf16*)alloc(MS_ * 1024 * 2);  // [B][h*64+d][S]
  bf16* AO    = (bf16*)alloc(MS_ * 1024 * 2);
  char* region = (char*)alloc(2 * MS_ * 1024 * 2 + MS_ * 16 * 8 + 1024);
  bf16* Opart = (bf16*)region;                           // [2][4096][1024] bf16 = 16MB
  float* ml   = (float*)(region + 2 * MS_ * 1024 * 2);   // [2][4096][16] float2 = 1MB
  float* MSc  = (float*)region;                          // aliased after combine
  bf16* MP    = (bf16*)(region + MS_ * 256 * 4);
  bf16* MO    = Kb;                                      // dead after attn
  bf16* CB    = Qb;                                      // dead after attn

  // 1: prep (Wq/bq pre-scaled)
  fused_prep<<<9479, 256, 0, stream>>>(X, Wq, Wk, Wv, Wo, Wma, Wmp, mask,
                                       bq, bk, bv, mv,
                                       Xb, Wqkvb, Wob, Wmab, Wmpb, M2, bqkv, mvTb);
  // 2: fused QKV projection, 128x128 m97 tile (V via LDS transpose, coalesced)
  gemm_qkv<<<dim3(24, 32), 256, 0, stream>>>(Xb, Wqkvb, bqkv, Qb, Kb, Vtb);
  // 3: attention, key-split x2 + combine
  attn_fwd<<<dim3(16, 16, 4), 256, 0, stream>>>(Qb, Kb, Vtb, M2, Opart, ml);
  attn_combine<<<4096, 256, 0, stream>>>(Opart, ml, AO);
  // 4-6: memory path
  gemm_bt<float, false><<<dim3(4, 32), 256, 0, stream>>>(Xb, Wmab, bma, nullptr, MSc, 4096, 256, 1024, 1.0f);
  softmax_rows256<<<1024, 256, 0, stream>>>(MSc, MP);
  gemm_bt<bf16, false><<<dim3(8, 32), 256, 0, stream>>>(MP, mvTb, nullptr, nullptr, MO, 4096, 512, 256, 1.0f);
  // 7: combined = attn_out + 0.3*(mem_out @ Wmp^T + bmp)
  gemm_bt<bf16, true><<<dim3(16, 32), 256, 0, stream>>>(MO, Wmpb, bmp, AO, CB, 4096, 1024, 512, 0.3f);
  // 8: final projection -> fp32 out
  gemm_bt<float, false><<<dim3(16, 32), 256, 0, stream>>>(CB, Wob, bo, nullptr, (float*)d_out, 4096, 1024, 1024, 1.0f);
}